// Round 5
// baseline (698.933 us; speedup 1.0000x reference)
//
#include <hip/hip_runtime.h>
#include <math.h>

#define C_CAP 1000000
#define DIM 64

// ws layout (float indices)
#define SCORES_OFF 0          // [1,000,000] raw scores
#define P1_OFF     1000000    // 2048 per-block triples {m, l, idx}, stride 4
#define HDR_OFF    1010000    // [0]=M, [1]=L_shift, [2]=argmax (int bits)
#define ACC_OFF    1010064    // [64] atomic accumulator
#define CNT_OFF    1010176    // 2 x u32 block-done counters (memset to 0)

#define NB1 2048              // 8 blocks/CU
#define NTILES (C_CAP / 16)   // 16 rows per wave-iteration in K1
#define NCHUNKS (C_CAP / 64)  // 64 rows per wave-iteration in K3
#define NWAVES (NB1 * 4)

// ---------------------------------------------------------------------------
// K1: stream keys, write raw scores, accumulate UNSHIFTED sum(exp(s)) (max
// score ~42 -> sum <= ~1e19, safe in fp32) + per-block max/argmax. Register
// double-buffer: the NEXT 16-row tile (4 x dwordx4, 4 KB) is loaded before
// the current tile is processed, so VMEM latency overlaps the shuffle/exp
// work (round-3 lesson: without this the scheduler sinks loads to their use,
// VGPR=32, and the wave stalls a full miss latency per tile).
// Tail: last-done block reduces the 2048 triples -> header, zeros acc.
// ---------------------------------------------------------------------------
__global__ __launch_bounds__(256, 8) void nd_scores(
    const float* __restrict__ query,
    const float* __restrict__ keys,
    float* __restrict__ ws)
{
    const int tid  = threadIdx.x;
    const int lane = tid & 63;
    const int wave = tid >> 6;
    const int cl   = lane & 15;
    const int g    = lane >> 4;
    const int wglobal = blockIdx.x * 4 + wave;

    const float4 q4 = ((const float4*)query)[cl];
    const float4* __restrict__ k4p = (const float4*)keys;

    float m = -1e30f, l = 0.f;
    int idx = 0;

    int t = wglobal;
    float4 kc[4];
    if (t < NTILES) {
        const float4* __restrict__ kp = k4p + (size_t)t * 256 + lane;
        #pragma unroll
        for (int j = 0; j < 4; ++j) kc[j] = kp[j * 64];
    }
    while (t < NTILES) {
        const int tn = t + NWAVES;
        float4 kn[4];
        if (tn < NTILES) {
            const float4* __restrict__ kp = k4p + (size_t)tn * 256 + lane;
            #pragma unroll
            for (int j = 0; j < 4; ++j) kn[j] = kp[j * 64];
        }

        float s[4];
        #pragma unroll
        for (int j = 0; j < 4; ++j)
            s[j] = fmaf(kc[j].x, q4.x,
                   fmaf(kc[j].y, q4.y,
                   fmaf(kc[j].z, q4.z, kc[j].w * q4.w)));
        // 4 independent 4-deep reduction chains, interleaved
        #pragma unroll
        for (int off = 1; off <= 8; off <<= 1) {
            #pragma unroll
            for (int j = 0; j < 4; ++j) s[j] += __shfl_xor(s[j], off);
        }

        // lane (g, cl=j) writes row 16t + 4j + g
        const float sv = (cl == 0) ? s[0] : (cl == 1) ? s[1]
                       : (cl == 2) ? s[2] : s[3];
        if (cl < 4) ws[SCORES_OFF + (size_t)t * 16 + 4 * cl + g] = sv;

        const float p0 = __expf(s[0]), p1 = __expf(s[1]);
        const float p2 = __expf(s[2]), p3 = __expf(s[3]);
        l += (p0 + p1) + (p2 + p3);

        const int rbase = t * 16 + g;
        #pragma unroll
        for (int j = 0; j < 4; ++j)
            if (s[j] > m) { m = s[j]; idx = rbase + 4 * j; }

        t = tn;
        #pragma unroll
        for (int j = 0; j < 4; ++j) kc[j] = kn[j];
    }

    // cross-group combine inside the wave
    #pragma unroll
    for (int off = 16; off <= 32; off <<= 1) {
        l += __shfl_xor(l, off);
        const float mo = __shfl_xor(m, off);
        const int  io  = __shfl_xor(idx, off);
        if (mo > m) { m = mo; idx = io; }
    }

    __shared__ float s_m[4], s_l[4];
    __shared__ int   s_idx[4];
    __shared__ int   s_last;
    if (lane == 0) { s_m[wave] = m; s_l[wave] = l; s_idx[wave] = idx; }
    __syncthreads();
    if (tid == 0) {
        float bm = s_m[0], bl = s_l[0]; int bi = s_idx[0];
        #pragma unroll
        for (int wv = 1; wv < 4; ++wv) {
            bl += s_l[wv];
            if (s_m[wv] > bm) { bm = s_m[wv]; bi = s_idx[wv]; }
        }
        float* bp = ws + P1_OFF + (size_t)blockIdx.x * 4;
        __hip_atomic_store(bp + 0, bm, __ATOMIC_RELAXED, __HIP_MEMORY_SCOPE_AGENT);
        __hip_atomic_store(bp + 1, bl, __ATOMIC_RELAXED, __HIP_MEMORY_SCOPE_AGENT);
        __hip_atomic_store((int*)bp + 2, bi, __ATOMIC_RELAXED, __HIP_MEMORY_SCOPE_AGENT);
        unsigned* cnt = (unsigned*)(ws + CNT_OFF);
        const unsigned prev = __hip_atomic_fetch_add(
            cnt, 1u, __ATOMIC_ACQ_REL, __HIP_MEMORY_SCOPE_AGENT);
        s_last = (prev == NB1 - 1);
    }
    __syncthreads();
    if (!s_last) return;

    // ---- last block: global reduce of the 2048 triples (fused old K2) ----
    float rm = -1e30f, rl = 0.f; int ri = 0;
    for (int b = tid; b < NB1; b += 256) {
        const float* bp = ws + P1_OFF + (size_t)b * 4;
        const float bm = __hip_atomic_load(bp + 0, __ATOMIC_RELAXED, __HIP_MEMORY_SCOPE_AGENT);
        const float bl = __hip_atomic_load(bp + 1, __ATOMIC_RELAXED, __HIP_MEMORY_SCOPE_AGENT);
        const int   bi = __hip_atomic_load((const int*)bp + 2, __ATOMIC_RELAXED, __HIP_MEMORY_SCOPE_AGENT);
        rl += bl;
        if (bm > rm) { rm = bm; ri = bi; }
    }
    __shared__ float rsm[256], rsl[256];
    __shared__ int   rsi[256];
    rsm[tid] = rm; rsl[tid] = rl; rsi[tid] = ri;
    __syncthreads();
    for (int st = 128; st > 0; st >>= 1) {
        if (tid < st) {
            rsl[tid] += rsl[tid + st];
            if (rsm[tid + st] > rsm[tid]) { rsm[tid] = rsm[tid + st]; rsi[tid] = rsi[tid + st]; }
        }
        __syncthreads();
    }
    if (tid == 0) {
        const float M = rsm[0];
        ws[HDR_OFF + 0] = M;
        ws[HDR_OFF + 1] = rsl[0] * __expf(-M);   // L_shift = sum(exp(s-M))
        ((int*)ws)[HDR_OFF + 2] = rsi[0];
    }
    if (tid < 64) ws[ACC_OFF + tid] = 0.f;
}

// ---------------------------------------------------------------------------
// K3: selective P.V. Waves scan 64-score chunks; rows with exp(s-M) > 1e-10
// (~1e4 of 1e6) trigger a wave-coalesced 256B value-row load + fma.
// Tail: atomicAdd block partials into acc; last-done block finalizes out
// (fused old K4).
// ---------------------------------------------------------------------------
__global__ __launch_bounds__(256, 8) void nd_pv(
    const float* __restrict__ values,
    float* __restrict__ ws, float* __restrict__ out)
{
    const int tid  = threadIdx.x;
    const int lane = tid & 63;
    const int wave = tid >> 6;
    const int wglobal = blockIdx.x * 4 + wave;

    const float M = ws[HDR_OFF];
    float acc = 0.f;

    for (int c = wglobal; c < NCHUNKS; c += NWAVES) {
        const float s = ws[SCORES_OFF + (size_t)c * 64 + lane];
        const float w = __expf(s - M);
        unsigned long long mask = __ballot(w > 1e-10f);
        while (mask) {
            const int b = __ffsll((long long)mask) - 1;
            mask &= mask - 1;
            const float wb = __shfl(w, b);
            acc = fmaf(wb, values[((size_t)c * 64 + b) * 64 + lane], acc);
        }
    }

    __shared__ float sA[4][64];
    __shared__ int   s_last;
    sA[wave][lane] = acc;
    __syncthreads();
    if (tid < 64) {
        const float v = sA[0][tid] + sA[1][tid] + sA[2][tid] + sA[3][tid];
        if (v != 0.f) atomicAdd(ws + ACC_OFF + tid, v);
    }
    __threadfence();   // drain the atomics before signaling done
    __syncthreads();
    if (tid == 0) {
        unsigned* cnt = (unsigned*)(ws + CNT_OFF) + 1;
        const unsigned prev = __hip_atomic_fetch_add(
            cnt, 1u, __ATOMIC_ACQ_REL, __HIP_MEMORY_SCOPE_AGENT);
        s_last = (prev == NB1 - 1);
    }
    __syncthreads();
    if (!s_last) return;

    // ---- last block: finalize ----
    if (tid < 64) {
        const float a = __hip_atomic_load(ws + ACC_OFF + tid,
                                          __ATOMIC_RELAXED, __HIP_MEMORY_SCOPE_AGENT);
        out[tid] = a / ws[HDR_OFF + 1];
    }
    if (tid == 64) out[64] = (float)((const int*)ws)[HDR_OFF + 2];
}

extern "C" void kernel_launch(void* const* d_in, const int* in_sizes, int n_in,
                              void* d_out, int out_size, void* d_ws, size_t ws_size,
                              hipStream_t stream) {
    const float* query  = (const float*)d_in[0];
    const float* keys   = (const float*)d_in[1];
    const float* values = (const float*)d_in[2];
    float* out = (float*)d_out;
    float* ws  = (float*)d_ws;

    // zero the two block-done counters (ws is poisoned 0xAA each iteration)
    hipMemsetAsync((char*)d_ws + (size_t)CNT_OFF * sizeof(float), 0, 8, stream);

    nd_scores<<<NB1, 256, 0, stream>>>(query, keys, ws);
    nd_pv<<<NB1, 256, 0, stream>>>(values, ws, out);
}